// Round 10
// baseline (181.955 us; speedup 1.0000x reference)
//
#include <hip/hip_runtime.h>
#include <hip/hip_bf16.h>
#include <cstdint>
#include <cstddef>

// Problem constants
#define BDIM   32768
#define KDIM   2048
#define NDIM   128
#define VHEADS 20
#define PDIM   6
#define RLORA  10

#define BM     16
#define BK     64
#define NCH    (KDIM / BK)                  // 32
#define OUT_ELEMS   (BDIM * VHEADS * PDIM)  // 3932160
#define WS_W_BYTES  (KDIM * NDIM * 2)       // 524288

typedef __attribute__((ext_vector_type(8))) __bf16 bf16x8;
typedef __attribute__((ext_vector_type(4))) float f32x4;
typedef __attribute__((ext_vector_type(2))) float f32x2;
typedef __attribute__((ext_vector_type(4))) unsigned int u32x4;

union FragU { bf16x8 b; u32x4 u; };

__device__ __forceinline__ unsigned int cvt_pk_bf16(float lo, float hi) {
  unsigned int r;
  asm("v_cvt_pk_bf16_f32 %0, %1, %2" : "=v"(r) : "v"(lo), "v"(hi));
  return r;
}

__device__ __forceinline__ void gload_lds16(const void* g, void* l) {
  __builtin_amdgcn_global_load_lds(
      (const __attribute__((address_space(1))) void*)(g),
      (__attribute__((address_space(3))) void*)(l), 16, 0, 0);
}

__device__ __forceinline__ float fast_tanh(float x) {
  float ax = fabsf(x);
  float e  = __expf(-2.0f * ax);
  float t  = __fdividef(1.0f - e, 1.0f + e);
  return copysignf(t, x);
}

// ---------------------------------------------------------------------------
// k0: pack We1 f32[2048][128] -> bf16 in B-FRAGMENT-MAJOR order:
//   n = nt*16 + (lane&15), k = c*64 + ks*32 + (lane>>4)*8 + j.
//   Chunk c = 16 KB at c*16384; fragment (nt,ks) at (nt*2+ks)*1024 + lane*16.
// Also M = lora_A @ lora_B ([2][120]).
// ---------------------------------------------------------------------------
__global__ __launch_bounds__(256)
void k0_pack(const float* __restrict__ We1,
             const float* __restrict__ lA,
             const float* __restrict__ lB,
             unsigned short* __restrict__ wsw,
             float* __restrict__ wsM) {
  if (blockIdx.x == 128) {
    int t = threadIdx.x;
    if (t < 2 * VHEADS * PDIM) {
      int d  = t / (VHEADS * PDIM);
      int vp = t - d * (VHEADS * PDIM);
      float s = 0.f;
#pragma unroll
      for (int r = 0; r < RLORA; ++r)
        s = fmaf(lA[d * RLORA + r], lB[r * (VHEADS * PDIM) + vp], s);
      wsM[t] = s;  // layout [d][vp]
    }
    return;
  }
  int t    = blockIdx.x * 256 + threadIdx.x;  // 0..32767
  int lane = t & 63;
  int blk  = t >> 6;                          // 0..511
  int ks   = blk & 1;
  int nt   = (blk >> 1) & 7;
  int c    = blk >> 4;
  int n    = nt * 16 + (lane & 15);
  int kb   = c * 64 + ks * 32 + (lane >> 4) * 8;

  unsigned int u[4];
#pragma unroll
  for (int q = 0; q < 4; ++q) {
    float f0 = We1[(size_t)(kb + 2 * q + 0) * NDIM + n];
    float f1 = We1[(size_t)(kb + 2 * q + 1) * NDIM + n];
    __hip_bfloat16 h0 = __float2bfloat16(f0);
    __hip_bfloat16 h1 = __float2bfloat16(f1);
    u[q] = (unsigned int)*reinterpret_cast<unsigned short*>(&h0) |
           ((unsigned int)*reinterpret_cast<unsigned short*>(&h1) << 16);
  }
  *reinterpret_cast<u32x4*>(wsw + (size_t)t * 8) = u32x4{u[0], u[1], u[2], u[3]};
}

// ---------------------------------------------------------------------------
// k1: fused encoder + heads.  WAVE-PRIVATE, BARRIER-FREE DMA pipeline.
//   2048 blocks x 64 threads (1 wave).  Wave owns 16 rows x 128 cols x K2048.
//   Per chunk (BK=64): A = 4 KB f32 (4 DMA, XOR-swizzled source granules),
//   B = 16 KB fragment pack (16 DMA).  Double-buffered in FOUR DISTINCT
//   __shared__ arrays (A0/A1/B0/B1) with the loop unrolled x2 so every LDS
//   address is compile-time-distinct -> compiler can prove no alias between
//   ds_reads and in-flight DMA -> counted s_waitcnt vmcnt(20) sticks.
//   NO s_barrier in the loop: the wave only reads LDS it wrote itself.
//   LDS = 40960 B exactly -> 4 blocks/CU; 80 KB DMA in flight per CU.
//   Epilogue: in-wave shfl z-reduce -> z; heads (slot=lane>>4, 5 heads each).
// ---------------------------------------------------------------------------
__global__ __launch_bounds__(64)
void k1_fused(const float* __restrict__ x,
              const unsigned short* __restrict__ wp,
              const float* __restrict__ be1,
              const float* __restrict__ We2,
              const float* __restrict__ be2,
              const float* __restrict__ W1,
              const float* __restrict__ b1,
              const float* __restrict__ W2,
              const float* __restrict__ b2,
              const float* __restrict__ M,
              float* __restrict__ out,
              float* __restrict__ zout) {
  __shared__ char A0[4096] __attribute__((aligned(16)));
  __shared__ char A1[4096] __attribute__((aligned(16)));
  __shared__ char B0[16384] __attribute__((aligned(16)));
  __shared__ char B1[16384] __attribute__((aligned(16)));

  const int lane = threadIdx.x;   // 0..63
  const int l15  = lane & 15;
  const int kgrp = lane >> 4;     // 0..3
  const int blk  = blockIdx.x;

  const float* xb = x + (size_t)blk * BM * KDIM;

  f32x4 acc[8];
#pragma unroll
  for (int i = 0; i < 8; ++i) acc[i] = f32x4{0.f, 0.f, 0.f, 0.f};

  // A stage: instr q covers rows q*4..q*4+3 (row = q*4 + lane>>4); dest is
  // linear (base + lane*16); source granule = (lane&15) ^ (row&7).
  auto STAGE = [&](char* Ad, char* Bd, int c) {
#pragma unroll
    for (int q = 0; q < 4; ++q) {
      int row = q * 4 + (lane >> 4);
      const float* s = xb + (size_t)row * KDIM + c * BK
                       + (((lane & 15) ^ (row & 7)) << 2);
      gload_lds16(s, Ad + q * 1024);
    }
#pragma unroll
    for (int i = 0; i < 16; ++i) {
      gload_lds16((const char*)wp + (size_t)c * 16384 + i * 1024 + lane * 16,
                  Bd + i * 1024);
    }
  };

  auto COMPUTE = [&](const char* Ad, const char* Bd) {
    const char* ab = Ad + l15 * 256;
    const int rx = l15 & 7;
    f32x4 lo0 = *(const f32x4*)(ab + (((kgrp * 2 + 0) ^ rx) << 4));
    f32x4 hi0 = *(const f32x4*)(ab + (((kgrp * 2 + 1) ^ rx) << 4));
    f32x4 lo1 = *(const f32x4*)(ab + ((((kgrp * 2 + 0) ^ rx) + 8) << 4));
    f32x4 hi1 = *(const f32x4*)(ab + ((((kgrp * 2 + 1) ^ rx) + 8) << 4));
    FragU a0, a1;
    a0.u = u32x4{cvt_pk_bf16(lo0.x, lo0.y), cvt_pk_bf16(lo0.z, lo0.w),
                 cvt_pk_bf16(hi0.x, hi0.y), cvt_pk_bf16(hi0.z, hi0.w)};
    a1.u = u32x4{cvt_pk_bf16(lo1.x, lo1.y), cvt_pk_bf16(lo1.z, lo1.w),
                 cvt_pk_bf16(hi1.x, hi1.y), cvt_pk_bf16(hi1.z, hi1.w)};
    const char* bb = Bd + lane * 16;
#pragma unroll
    for (int nt = 0; nt < 8; ++nt) {
      FragU b0, b1;
      b0.u = *(const u32x4*)(bb + (nt * 2 + 0) * 1024);
      b1.u = *(const u32x4*)(bb + (nt * 2 + 1) * 1024);
      acc[nt] = __builtin_amdgcn_mfma_f32_16x16x32_bf16(a0.b, b0.b, acc[nt], 0, 0, 0);
      acc[nt] = __builtin_amdgcn_mfma_f32_16x16x32_bf16(a1.b, b1.b, acc[nt], 0, 0, 0);
    }
  };

  // prologue: chunk 0 into A0/B0 (20 loads in flight)
  STAGE(A0, B0, 0);

#pragma unroll 1
  for (int cc = 0; cc < NCH / 2; ++cc) {
    STAGE(A1, B1, 2 * cc + 1);                 // +20 -> 40 outstanding
    asm volatile("s_waitcnt vmcnt(20)" ::: "memory");  // chunk 2cc landed
    __builtin_amdgcn_sched_barrier(0);
    COMPUTE(A0, B0);
    if (cc + 1 < NCH / 2) {
      STAGE(A0, B0, 2 * cc + 2);               // +20 -> 40 outstanding
      asm volatile("s_waitcnt vmcnt(20)" ::: "memory");  // chunk 2cc+1 landed
    } else {
      asm volatile("s_waitcnt vmcnt(0)" ::: "memory");   // final chunk landed
    }
    __builtin_amdgcn_sched_barrier(0);
    COMPUTE(A1, B1);
  }

  // ---- epilogue: +be1, relu, @We2, +be2 -> z for this wave's 16 rows
  float part[4][2];
#pragma unroll
  for (int j = 0; j < 4; ++j) { part[j][0] = 0.f; part[j][1] = 0.f; }
#pragma unroll
  for (int nt = 0; nt < 8; ++nt) {
    int col = nt * 16 + l15;
    float bb = be1[col];
    float w0 = We2[col * 2 + 0];
    float w1 = We2[col * 2 + 1];
#pragma unroll
    for (int j = 0; j < 4; ++j) {
      float h = acc[nt][j] + bb;
      h = h > 0.f ? h : 0.f;
      part[j][0] = fmaf(h, w0, part[j][0]);
      part[j][1] = fmaf(h, w1, part[j][1]);
    }
  }
#pragma unroll
  for (int m = 1; m < 16; m <<= 1) {
#pragma unroll
    for (int j = 0; j < 4; ++j) {
      part[j][0] += __shfl_xor(part[j][0], m, 64);
      part[j][1] += __shfl_xor(part[j][1], m, 64);
    }
  }
  float* zf = (float*)A0;   // reuse dead A buffer for z broadcast (16x2 f32)
  if (l15 == 0) {
    float bz0 = be2[0], bz1 = be2[1];
#pragma unroll
    for (int j = 0; j < 4; ++j) {
      int rl = kgrp * 4 + j;   // C row = (lane>>4)*4 + reg
      float zz0 = part[j][0] + bz0;
      float zz1 = part[j][1] + bz1;
      zf[rl * 2 + 0] = zz0;
      zf[rl * 2 + 1] = zz1;
      f32x2 zz = {zz0, zz1};
      *(f32x2*)(zout + (size_t)(blk * BM + rl) * 2) = zz;
    }
  }
  __syncthreads();   // 1-wave block: cheap; orders LDS z write -> read

  // ---- heads: row = lane&15, slot = lane>>4; head v = i*4 + slot
  const int srow = l15;
  const int slot = kgrp;
  float z0 = zf[srow * 2 + 0];
  float z1 = zf[srow * 2 + 1];
  float* orow = out + (size_t)(blk * BM + srow) * (VHEADS * PDIM);

#pragma unroll 1
  for (int i = 0; i < 5; ++i) {
    int v = i * 4 + slot;
    const float* w1a = W1 + (size_t)(v * 2 + 0) * NDIM;
    const float* w1b = W1 + (size_t)(v * 2 + 1) * NDIM;
    const float* bb1 = b1 + (size_t)v * NDIM;
    const float* w2  = W2 + (size_t)v * NDIM * PDIM;

    float p[6] = {0.f, 0.f, 0.f, 0.f, 0.f, 0.f};
#pragma unroll 4
    for (int h = 0; h < NDIM; ++h) {
      float hv = fmaf(z0, w1a[h], fmaf(z1, w1b[h], bb1[h]));
      hv = hv > 0.f ? hv : 0.f;
#pragma unroll
      for (int j = 0; j < 6; ++j) p[j] = fmaf(hv, w2[h * 6 + j], p[j]);
    }
    float o[6];
#pragma unroll
    for (int j = 0; j < 6; ++j) {
      float t1 = fast_tanh(p[j] + b2[v * PDIM + j]);
      float lo = fmaf(z0, M[v * PDIM + j], z1 * M[VHEADS * PDIM + v * PDIM + j]);
      o[j] = fast_tanh(fmaf(0.15f, lo, t1));
    }
    float* op = orow + v * PDIM;
    f32x2 o01 = {o[0], o[1]};
    f32x2 o23 = {o[2], o[3]};
    f32x2 o45 = {o[4], o[5]};
    __builtin_nontemporal_store(o01, (f32x2*)(op + 0));
    __builtin_nontemporal_store(o23, (f32x2*)(op + 2));
    __builtin_nontemporal_store(o45, (f32x2*)(op + 4));
  }
}

// ---------------------------------------------------------------------------
extern "C" void kernel_launch(void* const* d_in, const int* in_sizes, int n_in,
                              void* d_out, int out_size, void* d_ws, size_t ws_size,
                              hipStream_t stream) {
  const float* x   = (const float*)d_in[0];
  const float* We1 = (const float*)d_in[1];
  const float* be1 = (const float*)d_in[2];
  const float* We2 = (const float*)d_in[3];
  const float* be2 = (const float*)d_in[4];
  const float* W1  = (const float*)d_in[5];
  const float* b1  = (const float*)d_in[6];
  const float* W2  = (const float*)d_in[7];
  const float* b2  = (const float*)d_in[8];
  const float* lA  = (const float*)d_in[9];
  const float* lB  = (const float*)d_in[10];

  float* out  = (float*)d_out;
  float* zout = out + OUT_ELEMS;                       // second tuple output
  unsigned short* wsw = (unsigned short*)d_ws;         // 512 KB bf16 W pack
  float* wsM = (float*)((char*)d_ws + WS_W_BYTES);     // 240 floats

  hipLaunchKernelGGL(k0_pack, dim3(129), dim3(256), 0, stream,
                     We1, lA, lB, wsw, wsM);
  hipLaunchKernelGGL(k1_fused, dim3(BDIM / BM), dim3(64), 0, stream,
                     x, wsw, be1, We2, be2, W1, b1, W2, b2, wsM, out, zout);
}

// Round 11
// 159.050 us; speedup vs baseline: 1.1440x; 1.1440x over previous
//
#include <hip/hip_runtime.h>
#include <hip/hip_bf16.h>
#include <cstdint>
#include <cstddef>

// Problem constants
#define BDIM   32768
#define KDIM   2048
#define NDIM   128
#define VHEADS 20
#define PDIM   6
#define RLORA  10

#define BM     16
#define BK     32
#define NCH    (KDIM / BK)                  // 64 chunks of K=32
#define OUT_ELEMS   (BDIM * VHEADS * PDIM)  // 3932160
#define WS_W_BYTES  (KDIM * NDIM * 2)       // 524288

typedef __attribute__((ext_vector_type(8))) __bf16 bf16x8;
typedef __attribute__((ext_vector_type(4))) float f32x4;
typedef __attribute__((ext_vector_type(2))) float f32x2;
typedef __attribute__((ext_vector_type(4))) unsigned int u32x4;

union FragU { bf16x8 b; u32x4 u; };

__device__ __forceinline__ unsigned int cvt_pk_bf16(float lo, float hi) {
  unsigned int r;
  asm("v_cvt_pk_bf16_f32 %0, %1, %2" : "=v"(r) : "v"(lo), "v"(hi));
  return r;
}

__device__ __forceinline__ float fast_tanh(float x) {
  float ax = fabsf(x);
  float e  = __expf(-2.0f * ax);
  float t  = __fdividef(1.0f - e, 1.0f + e);
  return copysignf(t, x);
}

#define SBAR() __builtin_amdgcn_sched_barrier(0)

// ---------------------------------------------------------------------------
// k0: pack We1 f32[2048][128] -> bf16 in B-FRAGMENT-MAJOR order:
//   n = nt*16 + (lane&15), k = c64*64 + ks*32 + (lane>>4)*8 + j.
//   K32-chunk c: fragment nt at (c>>1)*16384 + (c&1)*1024 + nt*2048 + lane*16.
// Also M = lora_A @ lora_B ([2][120]).
// ---------------------------------------------------------------------------
__global__ __launch_bounds__(256)
void k0_pack(const float* __restrict__ We1,
             const float* __restrict__ lA,
             const float* __restrict__ lB,
             unsigned short* __restrict__ wsw,
             float* __restrict__ wsM) {
  if (blockIdx.x == 128) {
    int t = threadIdx.x;
    if (t < 2 * VHEADS * PDIM) {
      int d  = t / (VHEADS * PDIM);
      int vp = t - d * (VHEADS * PDIM);
      float s = 0.f;
#pragma unroll
      for (int r = 0; r < RLORA; ++r)
        s = fmaf(lA[d * RLORA + r], lB[r * (VHEADS * PDIM) + vp], s);
      wsM[t] = s;  // layout [d][vp]
    }
    return;
  }
  int t    = blockIdx.x * 256 + threadIdx.x;  // 0..32767
  int lane = t & 63;
  int blk  = t >> 6;                          // 0..511
  int ks   = blk & 1;
  int nt   = (blk >> 1) & 7;
  int c    = blk >> 4;
  int n    = nt * 16 + (lane & 15);
  int kb   = c * 64 + ks * 32 + (lane >> 4) * 8;

  unsigned int u[4];
#pragma unroll
  for (int q = 0; q < 4; ++q) {
    float f0 = We1[(size_t)(kb + 2 * q + 0) * NDIM + n];
    float f1 = We1[(size_t)(kb + 2 * q + 1) * NDIM + n];
    __hip_bfloat16 h0 = __float2bfloat16(f0);
    __hip_bfloat16 h1 = __float2bfloat16(f1);
    u[q] = (unsigned int)*reinterpret_cast<unsigned short*>(&h0) |
           ((unsigned int)*reinterpret_cast<unsigned short*>(&h1) << 16);
  }
  *reinterpret_cast<u32x4*>(wsw + (size_t)t * 8) = u32x4{u[0], u[1], u[2], u[3]};
}

// ---------------------------------------------------------------------------
// k1: fused encoder + heads.  ALL-REGISTER double-buffered pipeline.
//   2048 blocks x 64 threads (1 wave, 16 rows, full K).  NO LDS in the loop,
//   NO barriers.  Per K32 chunk: 2 A-dwordx4 (f32 direct from x) + 8
//   B-dwordx4 (bf16 fragment pack, L2-resident) into NAMED even/odd register
//   buffers.  sched_barrier(0) fences pin issue-early placement; the
//   compiler's own waitcnt insertion provides counted waits (it tracks each
//   load).  Occupancy limited only by VGPR (~3 waves/SIMD at <=170).
//   Epilogue: shfl z-reduce -> z; heads (slot = lane>>4, 5 heads each).
// ---------------------------------------------------------------------------
__global__ __launch_bounds__(64, 3)
void k1_fused(const float* __restrict__ x,
              const unsigned short* __restrict__ wp,
              const float* __restrict__ be1,
              const float* __restrict__ We2,
              const float* __restrict__ be2,
              const float* __restrict__ W1,
              const float* __restrict__ b1,
              const float* __restrict__ W2,
              const float* __restrict__ b2,
              const float* __restrict__ M,
              float* __restrict__ out,
              float* __restrict__ zout) {
  __shared__ float zf[32];

  const int lane = threadIdx.x;   // 0..63
  const int l15  = lane & 15;
  const int kgrp = lane >> 4;     // 0..3
  const int blk  = blockIdx.x;

  // A: lane reads its own MFMA fragment directly: row = blk*16 + l15,
  //    k = c*32 + kgrp*8 + {0..7}  (two dwordx4)
  const float* aptr = x + (size_t)(blk * BM + l15) * KDIM + kgrp * 8;
  // B: fragment nt of K32-chunk c at (c>>1)*16384 + (c&1)*1024 + nt*2048
  const char* bptr = (const char*)wp + lane * 16;

  f32x4 acc[8];
#pragma unroll
  for (int i = 0; i < 8; ++i) acc[i] = f32x4{0.f, 0.f, 0.f, 0.f};

  f32x4 aE[2], aO[2];
  FragU bE[8], bO[8];

  auto LOADA = [&](f32x4* A, int c) {
    const float* p = aptr + c * BK;
    A[0] = *(const f32x4*)(p);
    A[1] = *(const f32x4*)(p + 4);
  };
  auto LOADB = [&](FragU* B, int c) {
    const char* base = bptr + (size_t)(c >> 1) * 16384 + (c & 1) * 1024;
#pragma unroll
    for (int nt = 0; nt < 8; ++nt)
      B[nt].u = *(const u32x4*)(base + nt * 2048);
  };
  auto COMPUTE = [&](const f32x4* A, const FragU* B) {
    FragU a;
    a.u = u32x4{cvt_pk_bf16(A[0].x, A[0].y), cvt_pk_bf16(A[0].z, A[0].w),
                cvt_pk_bf16(A[1].x, A[1].y), cvt_pk_bf16(A[1].z, A[1].w)};
#pragma unroll
    for (int nt = 0; nt < 8; ++nt)
      acc[nt] = __builtin_amdgcn_mfma_f32_16x16x32_bf16(a.b, B[nt].b, acc[nt], 0, 0, 0);
  };

  // prologue: chunk 0 in flight
  LOADA(aE, 0);
  LOADB(bE, 0);
  SBAR();

#pragma unroll 1
  for (int cc = 0; cc < NCH / 2; ++cc) {
    // issue chunk 2cc+1, then compute chunk 2cc (its loads are the oldest)
    LOADA(aO, 2 * cc + 1);
    LOADB(bO, 2 * cc + 1);
    SBAR();
    COMPUTE(aE, bE);
    SBAR();
    if (cc + 1 < NCH / 2) {
      LOADA(aE, 2 * cc + 2);
      LOADB(bE, 2 * cc + 2);
    }
    SBAR();
    COMPUTE(aO, bO);
    SBAR();
  }

  // ---- epilogue: +be1, relu, @We2, +be2 -> z for this wave's 16 rows
  float part[4][2];
#pragma unroll
  for (int j = 0; j < 4; ++j) { part[j][0] = 0.f; part[j][1] = 0.f; }
#pragma unroll
  for (int nt = 0; nt < 8; ++nt) {
    int col = nt * 16 + l15;
    float bb = be1[col];
    float w0 = We2[col * 2 + 0];
    float w1 = We2[col * 2 + 1];
#pragma unroll
    for (int j = 0; j < 4; ++j) {
      float h = acc[nt][j] + bb;
      h = h > 0.f ? h : 0.f;
      part[j][0] = fmaf(h, w0, part[j][0]);
      part[j][1] = fmaf(h, w1, part[j][1]);
    }
  }
#pragma unroll
  for (int m = 1; m < 16; m <<= 1) {
#pragma unroll
    for (int j = 0; j < 4; ++j) {
      part[j][0] += __shfl_xor(part[j][0], m, 64);
      part[j][1] += __shfl_xor(part[j][1], m, 64);
    }
  }
  if (l15 == 0) {
    float bz0 = be2[0], bz1 = be2[1];
#pragma unroll
    for (int j = 0; j < 4; ++j) {
      int rl = kgrp * 4 + j;   // C row = (lane>>4)*4 + reg
      float zz0 = part[j][0] + bz0;
      float zz1 = part[j][1] + bz1;
      zf[rl * 2 + 0] = zz0;
      zf[rl * 2 + 1] = zz1;
      f32x2 zz = {zz0, zz1};
      *(f32x2*)(zout + (size_t)(blk * BM + rl) * 2) = zz;
    }
  }
  __syncthreads();   // 1-wave block: orders LDS z write -> read

  // ---- heads: row = lane&15, slot = lane>>4; head v = i*4 + slot
  const int srow = l15;
  const int slot = kgrp;
  float z0 = zf[srow * 2 + 0];
  float z1 = zf[srow * 2 + 1];
  float* orow = out + (size_t)(blk * BM + srow) * (VHEADS * PDIM);

#pragma unroll 1
  for (int i = 0; i < 5; ++i) {
    int v = i * 4 + slot;
    const float* w1a = W1 + (size_t)(v * 2 + 0) * NDIM;
    const float* w1b = W1 + (size_t)(v * 2 + 1) * NDIM;
    const float* bb1 = b1 + (size_t)v * NDIM;
    const float* w2  = W2 + (size_t)v * NDIM * PDIM;

    float p[6] = {0.f, 0.f, 0.f, 0.f, 0.f, 0.f};
#pragma unroll 4
    for (int h = 0; h < NDIM; ++h) {
      float hv = fmaf(z0, w1a[h], fmaf(z1, w1b[h], bb1[h]));
      hv = hv > 0.f ? hv : 0.f;
#pragma unroll
      for (int j = 0; j < 6; ++j) p[j] = fmaf(hv, w2[h * 6 + j], p[j]);
    }
    float o[6];
#pragma unroll
    for (int j = 0; j < 6; ++j) {
      float t1 = fast_tanh(p[j] + b2[v * PDIM + j]);
      float lo = fmaf(z0, M[v * PDIM + j], z1 * M[VHEADS * PDIM + v * PDIM + j]);
      o[j] = fast_tanh(fmaf(0.15f, lo, t1));
    }
    float* op = orow + v * PDIM;
    f32x2 o01 = {o[0], o[1]};
    f32x2 o23 = {o[2], o[3]};
    f32x2 o45 = {o[4], o[5]};
    __builtin_nontemporal_store(o01, (f32x2*)(op + 0));
    __builtin_nontemporal_store(o23, (f32x2*)(op + 2));
    __builtin_nontemporal_store(o45, (f32x2*)(op + 4));
  }
}

// ---------------------------------------------------------------------------
extern "C" void kernel_launch(void* const* d_in, const int* in_sizes, int n_in,
                              void* d_out, int out_size, void* d_ws, size_t ws_size,
                              hipStream_t stream) {
  const float* x   = (const float*)d_in[0];
  const float* We1 = (const float*)d_in[1];
  const float* be1 = (const float*)d_in[2];
  const float* We2 = (const float*)d_in[3];
  const float* be2 = (const float*)d_in[4];
  const float* W1  = (const float*)d_in[5];
  const float* b1  = (const float*)d_in[6];
  const float* W2  = (const float*)d_in[7];
  const float* b2  = (const float*)d_in[8];
  const float* lA  = (const float*)d_in[9];
  const float* lB  = (const float*)d_in[10];

  float* out  = (float*)d_out;
  float* zout = out + OUT_ELEMS;                       // second tuple output
  unsigned short* wsw = (unsigned short*)d_ws;         // 512 KB bf16 W pack
  float* wsM = (float*)((char*)d_ws + WS_W_BYTES);     // 240 floats

  hipLaunchKernelGGL(k0_pack, dim3(129), dim3(256), 0, stream,
                     We1, lA, lB, wsw, wsM);
  hipLaunchKernelGGL(k1_fused, dim3(BDIM / BM), dim3(64), 0, stream,
                     x, wsw, be1, We2, be2, W1, b1, W2, b2, wsM, out, zout);
}